// Round 1
// baseline (732.183 us; speedup 1.0000x reference)
//
#include <hip/hip_runtime.h>
#include <math.h>

#define DIM   2048
#define NREF  30
#define BATCH 16384
#define KPAD  32

// Workspace float offsets
#define WS_VN   0         // 30*2048      normalized vectors, [k][d]
#define WS_G    61440     // 900          Gram matrix
#define WS_T    62464     // 900          T (upper-tri 30x30)
#define WS_W2   63488     // 2048*32      W = V*T, layout [d][KPAD]
#define WS_VNT  129024    // 2048*32      V^T, layout [d][KPAD]
#define WS_S    194560    // 16384*32     S = x*W, layout [r][KPAD]
// total floats: 718848 -> ~2.88 MB of d_ws

__device__ __forceinline__ float block_reduce_sum(float s) {
    // wave64 reduce
    #pragma unroll
    for (int off = 32; off > 0; off >>= 1) s += __shfl_down(s, off);
    __shared__ float ws4[4];
    int t = threadIdx.x;
    if ((t & 63) == 0) ws4[t >> 6] = s;
    __syncthreads();
    return ws4[0] + ws4[1] + ws4[2] + ws4[3];
}

// ---- k0: vn_i = v_i / (||v_i|| + 1e-8) ----
__global__ void k_normalize(const float* __restrict__ vec, float* __restrict__ vn) {
    int i = blockIdx.x;
    int t = threadIdx.x;
    const float* v = vec + i * DIM;
    float s = 0.f;
    for (int d = t; d < DIM; d += 256) { float xv = v[d]; s += xv * xv; }
    float tot = block_reduce_sum(s);
    float scale = 1.f / (sqrtf(tot) + 1e-8f);
    float* o = vn + i * DIM;
    for (int d = t; d < DIM; d += 256) o[d] = v[d] * scale;
}

// ---- k1: G[i][j] = vn_i . vn_j ----
__global__ void k_gram(const float* __restrict__ vn, float* __restrict__ G) {
    int j = blockIdx.x, i = blockIdx.y;
    int t = threadIdx.x;
    const float* a = vn + i * DIM;
    const float* b = vn + j * DIM;
    float s = 0.f;
    for (int d = t; d < DIM; d += 256) s += a[d] * b[d];
    float tot = block_reduce_sum(s);
    if (t == 0) G[i * NREF + j] = tot;
}

// ---- k2: build T (upper triangular, tau = 2) ----
// T[j][j] = 2 ; T[i][j] = -2 * sum_{m=i}^{j-1} T[i][m] * G[m][j]  (i < j)
__global__ void k_T(const float* __restrict__ G, float* __restrict__ T) {
    int t = threadIdx.x;  // 64 threads (one wave)
    __shared__ float Ts[NREF][NREF];
    for (int idx = t; idx < NREF * NREF; idx += 64) Ts[idx / NREF][idx % NREF] = 0.f;
    __syncthreads();
    if (t == 0) Ts[0][0] = 2.f;
    __syncthreads();
    for (int j = 1; j < NREF; j++) {
        float val = 0.f;
        if (t < j) {
            for (int m = t; m < j; m++) val += Ts[t][m] * G[m * NREF + j];
            val *= -2.f;
        }
        if (t < j) Ts[t][j] = val;
        if (t == j) Ts[j][j] = 2.f;
        __syncthreads();
    }
    for (int idx = t; idx < NREF * NREF; idx += 64) T[idx] = Ts[idx / NREF][idx % NREF];
}

// ---- k3: W2[d][k] = sum_{j<=k} vn[j][d]*T[j][k] ; vnT[d][k] = vn[k][d] ----
__global__ void k_w2(const float* __restrict__ vn, const float* __restrict__ T,
                     float* __restrict__ W2, float* __restrict__ vnT) {
    int d = blockIdx.x * 256 + threadIdx.x;  // 0..2047
    float vr[NREF];
    #pragma unroll
    for (int j = 0; j < NREF; j++) vr[j] = vn[j * DIM + d];
    #pragma unroll
    for (int k = 0; k < NREF; k++) {
        float acc = 0.f;
        for (int j = 0; j <= k; j++) acc += vr[j] * T[j * NREF + k];
        W2[(size_t)d * KPAD + k]  = acc;
        vnT[(size_t)d * KPAD + k] = vr[k];
    }
}

// ---- phase 1: S[r][k] = sum_d x[r][d] * W2[d][k] ----
// Block: 256 thr = 4 waves. Lane = row (64 rows/block), wave = K-quarter (512 d's).
// W2 reads are wave-uniform -> scalar loads. Cross-wave reduce via LDS.
__global__ __launch_bounds__(256) void k_phase1(const float* __restrict__ x,
                                                const float* __restrict__ W2,
                                                float* __restrict__ S) {
    int tid = threadIdx.x;
    int wave = tid >> 6, lane = tid & 63;
    int row = blockIdx.x * 64 + lane;
    const float4* xr = (const float4*)(x + (size_t)row * DIM + wave * 512);

    float acc[NREF];
    #pragma unroll
    for (int k = 0; k < NREF; k++) acc[k] = 0.f;

    for (int c = 0; c < 128; c++) {
        float4 x4 = xr[c];
        int d = wave * 512 + c * 4;
        const float* w0 = W2 + (size_t)d * KPAD;
        #pragma unroll
        for (int k = 0; k < NREF; k++)
            acc[k] += x4.x * w0[k] + x4.y * w0[KPAD + k]
                    + x4.z * w0[2 * KPAD + k] + x4.w * w0[3 * KPAD + k];
    }

    __shared__ float red[4][64][NREF];  // 30 KB
    #pragma unroll
    for (int k = 0; k < NREF; k++) red[wave][lane][k] = acc[k];
    __syncthreads();
    if (tid < 64) {
        size_t r = (size_t)blockIdx.x * 64 + tid;
        #pragma unroll
        for (int k = 0; k < NREF; k++)
            S[r * KPAD + k] = red[0][tid][k] + red[1][tid][k]
                            + red[2][tid][k] + red[3][tid][k];
    }
}

// ---- phase 2: y[r][d] = x[r][d] + bias[d] - sum_k S[r][k] * vnT[d][k] ----
// Lane = row, wave = column-quarter. S cached in 30 VGPRs/lane; vnT/bias uniform.
__global__ __launch_bounds__(256) void k_phase2(const float* __restrict__ x,
                                                const float* __restrict__ S,
                                                const float* __restrict__ vnT,
                                                const float* __restrict__ bias,
                                                float* __restrict__ y) {
    int tid = threadIdx.x;
    int wave = tid >> 6, lane = tid & 63;
    int row = blockIdx.x * 64 + lane;
    size_t rbase = (size_t)row * DIM + wave * 512;
    const float4* xr = (const float4*)(x + rbase);
    float4* yr = (float4*)(y + rbase);

    float s[NREF];
    #pragma unroll
    for (int k = 0; k < NREF; k++) s[k] = S[(size_t)row * KPAD + k];

    for (int c = 0; c < 128; c++) {
        float4 x4 = xr[c];
        int d = wave * 512 + c * 4;
        const float* vt = vnT + (size_t)d * KPAD;
        float4 o;
        o.x = x4.x + bias[d + 0];
        o.y = x4.y + bias[d + 1];
        o.z = x4.z + bias[d + 2];
        o.w = x4.w + bias[d + 3];
        #pragma unroll
        for (int k = 0; k < NREF; k++) {
            o.x -= s[k] * vt[k];
            o.y -= s[k] * vt[KPAD + k];
            o.z -= s[k] * vt[2 * KPAD + k];
            o.w -= s[k] * vt[3 * KPAD + k];
        }
        yr[c] = o;
    }
}

extern "C" void kernel_launch(void* const* d_in, const int* in_sizes, int n_in,
                              void* d_out, int out_size, void* d_ws, size_t ws_size,
                              hipStream_t stream) {
    const float* x    = (const float*)d_in[0];
    const float* vec  = (const float*)d_in[1];
    const float* bias = (const float*)d_in[2];
    float* out = (float*)d_out;
    float* ws  = (float*)d_ws;

    float* vn  = ws + WS_VN;
    float* G   = ws + WS_G;
    float* T   = ws + WS_T;
    float* W2  = ws + WS_W2;
    float* vnT = ws + WS_VNT;
    float* S   = ws + WS_S;

    k_normalize<<<NREF, 256, 0, stream>>>(vec, vn);
    k_gram<<<dim3(NREF, NREF), 256, 0, stream>>>(vn, G);
    k_T<<<1, 64, 0, stream>>>(G, T);
    k_w2<<<DIM / 256, 256, 0, stream>>>(vn, T, W2, vnT);
    k_phase1<<<BATCH / 64, 256, 0, stream>>>(x, W2, S);
    k_phase2<<<BATCH / 64, 256, 0, stream>>>(x, S, vnT, bias, out);
}